// Round 11
// baseline (116.115 us; speedup 1.0000x reference)
//
#include <hip/hip_runtime.h>
#include <hip/hip_bf16.h>

// HardAttention = GEMM out=tanh([ctx|outp]@W^T+b) (M=16384,K=1024,N=512, bf16 MFMA)
//               + attn = constant one-hot [4,4096,4096] (256 MiB write stream).
// R9 fused best: 74.4us (~5 TB/s aggregate). R10 lesson: smaller tiles = redundant staging.
// R11 discriminating probe: PURE PHASES. (1) R9's GEMM unchanged minus fill stores;
// (2) memset-equivalent zero kernel (no one-hot VALU -> should match 7 TB/s harness fill);
// (3) tiny diagonal-ones kernel. Decides: was fused overlap real, or do pure phases win
// via avoided read<->write turnaround?

typedef __attribute__((ext_vector_type(8))) short bf16x8;   // 8 bf16 = 4 VGPRs
typedef __attribute__((ext_vector_type(4))) float f32x4;

#define B_N 4
#define L_N 4096
#define S_N 4096
#define D_N 512
#define M_N (B_N * L_N)   // 16384
#define K_N (2 * D_N)     // 1024

#define NTHREADS 256      // 4 waves/block
#define NBLOCKS 512       // 2048 waves total
#define NSTEPS 32         // K / 32

static __device__ __forceinline__ short f2bf(float f) {
  return __builtin_bit_cast(short, __float2bfloat16(f));   // RNE; fuses to v_cvt_pk_bf16_f32
}

static __device__ __forceinline__ bf16x8 pack8(f32x4 a, f32x4 b) {
  bf16x8 r;
  r[0] = f2bf(a.x); r[1] = f2bf(a.y); r[2] = f2bf(a.z); r[3] = f2bf(a.w);
  r[4] = f2bf(b.x); r[5] = f2bf(b.y); r[6] = f2bf(b.z); r[7] = f2bf(b.w);
  return r;
}

// ---------------- GEMM only (R9 structure, fill stores removed) ----------------
__global__ __launch_bounds__(NTHREADS, 2)
void gemm_only(const float* __restrict__ outp, const float* __restrict__ ctx,
               const float* __restrict__ Wm, const float* __restrict__ bias,
               float* __restrict__ dout)
{
  __shared__ char lds[4][8192];

  const int tid  = threadIdx.x;
  const int lane = tid & 63;
  const int wid  = tid >> 6;
  const int gwave = blockIdx.x * 4 + wid;
  const int mtile = gwave >> 3;       // 256 tiles of 64 rows
  const int ntile = gwave & 7;        // 8 tiles of 64 cols
  const int m0 = mtile * 64;
  const int n0 = ntile * 64;

  char* As = lds[wid];
  char* Ws = lds[wid] + 4096;

  const int lrq = lane >> 2;          // 0..15
  const int ch  = lane & 3;           // 0..3
  const int wrB  = lrq * 64 + ((ch << 4) ^ (((lrq >> 1) & 3) << 4));       // + q*1024
  const int rdB  = (lane & 15) * 64 +
                   ((((lane >> 4) << 4)) ^ ((((lane & 15) >> 1) & 3) << 4)); // + i*1024

  const float* aC = ctx  + (size_t)(m0 + lrq) * D_N + ch * 8;   // k-steps 0..15
  const float* aO = outp + (size_t)(m0 + lrq) * D_N + ch * 8;   // k-steps 16..31
  const float* wB = Wm   + (size_t)(n0 + lrq) * K_N + ch * 8;   // full k

  f32x4 acc[4][4] = {};
  f32x4 sa[8], sw[8];

#pragma unroll
  for (int q = 0; q < 4; ++q) {
    sa[2*q]   = *(const f32x4*)(aC + q * (16 * D_N));
    sa[2*q+1] = *(const f32x4*)(aC + q * (16 * D_N) + 4);
    sw[2*q]   = *(const f32x4*)(wB + q * (16 * K_N));
    sw[2*q+1] = *(const f32x4*)(wB + q * (16 * K_N) + 4);
  }

#pragma unroll 1
  for (int t = 0; t < NSTEPS; ++t) {
#pragma unroll
    for (int q = 0; q < 4; ++q) {
      *(bf16x8*)(As + q * 1024 + wrB) = pack8(sa[2*q], sa[2*q+1]);
      *(bf16x8*)(Ws + q * 1024 + wrB) = pack8(sw[2*q], sw[2*q+1]);
    }

    if (t + 1 < NSTEPS) {
      const int tn = t + 1;
      const float* ab = (tn < 16 ? aC : aO) + (tn & 15) * 32;
      const float* wb = wB + tn * 32;
#pragma unroll
      for (int q = 0; q < 4; ++q) {
        sa[2*q]   = *(const f32x4*)(ab + q * (16 * D_N));
        sa[2*q+1] = *(const f32x4*)(ab + q * (16 * D_N) + 4);
        sw[2*q]   = *(const f32x4*)(wb + q * (16 * K_N));
        sw[2*q+1] = *(const f32x4*)(wb + q * (16 * K_N) + 4);
      }
    }

    bf16x8 af[4], wf[4];
#pragma unroll
    for (int i = 0; i < 4; ++i) {
      af[i] = *(const bf16x8*)(As + i * 1024 + rdB);
      wf[i] = *(const bf16x8*)(Ws + i * 1024 + rdB);
    }
#pragma unroll
    for (int i = 0; i < 4; ++i)
#pragma unroll
      for (int j = 0; j < 4; ++j)
        acc[i][j] = __builtin_amdgcn_mfma_f32_16x16x32_bf16(af[i], wf[j], acc[i][j], 0, 0, 0);
  }

  const int r0  = m0 + ((lane >> 4) << 2);
  const int c0g = n0 + (lane & 15);
  float bv[4];
#pragma unroll
  for (int j = 0; j < 4; ++j) bv[j] = bias[c0g + j * 16];
#pragma unroll
  for (int i = 0; i < 4; ++i)
#pragma unroll
    for (int j = 0; j < 4; ++j)
#pragma unroll
      for (int r = 0; r < 4; ++r) {
        const int m = r0 + i * 16 + r;
        const int n = c0g + j * 16;
        dout[(size_t)m * D_N + n] = tanhf(acc[i][j][r] + bv[j]);
      }
}

// ---------------- attn zeros: memset-equivalent NT store stream ----------------
__global__ __launch_bounds__(NTHREADS)
void fill_zero(float* __restrict__ dout)
{
  f32x4* attn4 = (f32x4*)(dout + (size_t)M_N * D_N);
  const f32x4 z = {0.f, 0.f, 0.f, 0.f};
  const int i0 = blockIdx.x * NTHREADS + threadIdx.x;
  // 16,777,216 f32x4 / (2048*256) = 32 per thread; block-contiguous sweeps
#pragma unroll
  for (int k = 0; k < 32; ++k)
    __builtin_nontemporal_store(z, attn4 + (size_t)i0 + (size_t)k * (2048 * NTHREADS));
}

// ---------------- diagonal ones: attn[b, l, l] = 1.0f ----------------
__global__ __launch_bounds__(NTHREADS)
void diag_ones(float* __restrict__ dout)
{
  float* attn = dout + (size_t)M_N * D_N;
  const int i = blockIdx.x * NTHREADS + threadIdx.x;   // 16384 threads
  const int b = i >> 12;
  const int l = i & (L_N - 1);
  attn[(size_t)b * L_N * S_N + (size_t)l * S_N + l] = 1.0f;
}

extern "C" void kernel_launch(void* const* d_in, const int* in_sizes, int n_in,
                              void* d_out, int out_size, void* d_ws, size_t ws_size,
                              hipStream_t stream) {
  const float* outp = (const float*)d_in[0];
  const float* ctx  = (const float*)d_in[1];
  const float* Wm   = (const float*)d_in[2];
  const float* bias = (const float*)d_in[3];
  float* dout = (float*)d_out;
  hipLaunchKernelGGL(gemm_only, dim3(NBLOCKS), dim3(NTHREADS), 0, stream,
                     outp, ctx, Wm, bias, dout);
  hipLaunchKernelGGL(fill_zero, dim3(2048), dim3(NTHREADS), 0, stream, dout);
  hipLaunchKernelGGL(diag_ones, dim3(M_N / NTHREADS), dim3(NTHREADS), 0, stream, dout);
}

// Round 12
// 77.355 us; speedup vs baseline: 1.5011x; 1.5011x over previous
//
#include <hip/hip_runtime.h>
#include <hip/hip_bf16.h>

// HardAttention = GEMM out=tanh([ctx|outp]@W^T+b) (M=16384,K=1024,N=512, bf16 MFMA)
//               + attn = constant one-hot [4,4096,4096] (256 MiB write stream).
// R11 decomposition: fill is roofline (~39us) and fully hidden in fused mode; the GEMM
// alone is ~74us and LATENCY-bound (depth-1 load pipeline, 2 waves/SIMD).
// R12: depth-2 async staging. A/W staged as f32 via global_load_lds into per-wave LDS
// (no VGPR cost), ring of 2 buffers, batch t+2 issued one full iteration ahead. Explicit
// counted s_waitcnt vmcnt ledger (no barriers anywhere -> fill stores never force-drained):
//   window t issues stores(t)=4 + loads(t+2)=16; at top of iter t, vmcnt(20) forces
//   loads(t) done while loads(t+1) stay in flight; t=31 -> vmcnt(4); prologue -> vmcnt(16).
// f32->bf16 cvt moved AFTER the swizzled ds_read (off the load-latency path).
// LDS swizzle (rule 21): linear gload_lds dest + inverse-swizzled per-lane SOURCE
// (LDS[r][s] = G[r][s^(r&7)]) + swizzled read -> 2-way banking (free) both sides.

typedef __attribute__((ext_vector_type(8))) short bf16x8;   // 8 bf16 = 4 VGPRs
typedef __attribute__((ext_vector_type(4))) float f32x4;

#define B_N 4
#define L_N 4096
#define S_N 4096
#define D_N 512
#define M_N (B_N * L_N)   // 16384
#define K_N (2 * D_N)     // 1024

#define NTHREADS 256      // 4 waves/block
#define NBLOCKS 512       // 2048 waves = 256 mtiles(64) x 8 ntiles(64)
#define NSTEPS 32         // K / 32

static __device__ __forceinline__ short f2bf(float f) {
  return __builtin_bit_cast(short, __float2bfloat16(f));   // RNE; fuses to v_cvt_pk_bf16_f32
}

static __device__ __forceinline__ bf16x8 pack8(f32x4 a, f32x4 b) {
  bf16x8 r;
  r[0] = f2bf(a.x); r[1] = f2bf(a.y); r[2] = f2bf(a.z); r[3] = f2bf(a.w);
  r[4] = f2bf(b.x); r[5] = f2bf(b.y); r[6] = f2bf(b.z); r[7] = f2bf(b.w);
  return r;
}

static __device__ __forceinline__ void gload16(const float* g, char* l) {
  __builtin_amdgcn_global_load_lds(
      (const __attribute__((address_space(1))) unsigned*)g,
      (__attribute__((address_space(3))) unsigned*)l, 16, 0, 0);
}

#define WAITV(N)                                                    \
  asm volatile("s_waitcnt vmcnt(" #N ")" ::: "memory");             \
  __builtin_amdgcn_sched_barrier(0)
#define WAITL0                                                      \
  asm volatile("s_waitcnt lgkmcnt(0)" ::: "memory");                \
  __builtin_amdgcn_sched_barrier(0)

__global__ __launch_bounds__(NTHREADS, 1)
void gemm_fill(const float* __restrict__ outp, const float* __restrict__ ctx,
               const float* __restrict__ Wm, const float* __restrict__ bias,
               float* __restrict__ dout)
{
  // per-wave 32KB: ring{2} x { A-tile 8KB (64r x 128B f32) , W-tile 8KB }
  __shared__ char lds[4 * 32768];   // 128 KiB -> 1 block/CU

  const int tid  = threadIdx.x;
  const int lane = tid & 63;
  const int wid  = tid >> 6;
  const int gwave = blockIdx.x * 4 + wid;
  const int mtile = gwave >> 3;       // 256 tiles of 64 rows
  const int ntile = gwave & 7;        // 8 tiles of 64 cols
  const int m0 = mtile * 64;
  const int n0 = ntile * 64;

  char* ldsBase = &lds[wid * 32768];

  // ---- staging source map (pre-swizzled, rule 21): instr i covers rows i*8..i*8+7.
  // lane l -> row r = i*8 + (l>>3), LDS slot s = l&7; source slot s' = s ^ (r&7).
  const int sprime   = (lane & 7) ^ (lane >> 3);
  const int aLaneOff = (m0 + (lane >> 3)) * D_N + sprime * 4;   // float units
  const int wLaneOff = (n0 + (lane >> 3)) * K_N + sprime * 4;

  // ---- read map: frag row R = i*16 + l15; global slot g read at LDS slot g^(R&7);
  // R&7 == l15&7 since i*16 % 8 == 0.
  const int l15 = lane & 15;
  const int lq  = lane >> 4;          // k-slice: f32 k = lq*8 .. +7 (slots 2lq, 2lq+1)
  const int x15 = l15 & 7;
  const int rd0 = l15 * 128 + (((lq * 2)     ^ x15) << 4);
  const int rd1 = l15 * 128 + (((lq * 2 + 1) ^ x15) << 4);

  // fill: this wave covers f32x4 indices [gwave*8192, (gwave+1)*8192)
  f32x4* attn4 = (f32x4*)(dout + (size_t)M_N * D_N) + (size_t)gwave * 8192;

  f32x4 acc[4][4] = {};

#define ISSUE(TT)                                                               \
  {                                                                             \
    const int tt_ = (TT);                                                       \
    const float* as_ = (tt_ < 16 ? ctx : outp) + aLaneOff + (tt_ & 15) * 32;    \
    const float* ws_ = Wm + wLaneOff + tt_ * 32;                                \
    char* db_ = ldsBase + (tt_ & 1) * 16384;                                    \
    _Pragma("unroll")                                                           \
    for (int i = 0; i < 8; ++i) {                                               \
      gload16(as_ + i * (8 * D_N), db_ + i * 1024);                             \
      gload16(ws_ + i * (8 * K_N), db_ + 8192 + i * 1024);                      \
    }                                                                           \
  }

  // ---- prologue: batches 0,1 in flight; ensure batch 0 landed ----
  ISSUE(0)
  ISSUE(1)
  WAITV(16);

#pragma unroll 1
  for (int t = 0; t < NSTEPS; ++t) {
    // ledger: windows t-1,t each contain 4 stores + 16 loads.
    if (t < NSTEPS - 1) { WAITV(20); }   // loads(t) done; loads(t+1) stay in flight
    else               { WAITV(4);  }    // last iter: only stores(30) may remain

    // ---- swizzled ds_read (f32) + cvt -> fragments ----
    const char* rb = ldsBase + (t & 1) * 16384;
    bf16x8 af[4], wf[4];
#pragma unroll
    for (int i = 0; i < 4; ++i) {
      f32x4 lo = *(const f32x4*)(rb + i * 2048 + rd0);
      f32x4 hi = *(const f32x4*)(rb + i * 2048 + rd1);
      af[i] = pack8(lo, hi);
    }
#pragma unroll
    for (int j = 0; j < 4; ++j) {
      f32x4 lo = *(const f32x4*)(rb + 8192 + j * 2048 + rd0);
      f32x4 hi = *(const f32x4*)(rb + 8192 + j * 2048 + rd1);
      wf[j] = pack8(lo, hi);
    }
    WAITL0;   // ds_reads retired -> buf[t&1] reusable by batch t+2

    // ---- window t: fill stores (4) + batch t+2 (16 loads) ----
#pragma unroll
    for (int s = 0; s < 4; ++s) {
      const int li = t * 256 + (s << 6) + lane;        // local f32x4 idx
      const int gi = (gwave << 13) + li;
      const int col4 = (gi & 1023) << 2;
      const int l    = (gi >> 10) & 4095;
      f32x4 v;
      v.x = (col4     == l) ? 1.0f : 0.0f;
      v.y = (col4 + 1 == l) ? 1.0f : 0.0f;
      v.z = (col4 + 2 == l) ? 1.0f : 0.0f;
      v.w = (col4 + 3 == l) ? 1.0f : 0.0f;
      __builtin_nontemporal_store(v, attn4 + li);
    }
    if (t + 2 < NSTEPS) ISSUE(t + 2)

    // ---- 16 MFMA ----
#pragma unroll
    for (int i = 0; i < 4; ++i)
#pragma unroll
      for (int j = 0; j < 4; ++j)
        acc[i][j] = __builtin_amdgcn_mfma_f32_16x16x32_bf16(af[i], wf[j], acc[i][j], 0, 0, 0);
  }
#undef ISSUE

  // ---- epilogue: C/D layout col=lane&15, row=(lane>>4)*4+reg (verified R1/m89/m91) ----
  const int r0  = m0 + (lq << 2);
  const int c0g = n0 + l15;
  float bv[4];
#pragma unroll
  for (int j = 0; j < 4; ++j) bv[j] = bias[c0g + j * 16];
#pragma unroll
  for (int i = 0; i < 4; ++i)
#pragma unroll
    for (int j = 0; j < 4; ++j)
#pragma unroll
      for (int r = 0; r < 4; ++r) {
        const int m = r0 + i * 16 + r;
        const int n = c0g + j * 16;
        dout[(size_t)m * D_N + n] = tanhf(acc[i][j][r] + bv[j]);
      }
}

extern "C" void kernel_launch(void* const* d_in, const int* in_sizes, int n_in,
                              void* d_out, int out_size, void* d_ws, size_t ws_size,
                              hipStream_t stream) {
  const float* outp = (const float*)d_in[0];
  const float* ctx  = (const float*)d_in[1];
  const float* Wm   = (const float*)d_in[2];
  const float* bias = (const float*)d_in[3];
  float* dout = (float*)d_out;
  hipLaunchKernelGGL(gemm_fill, dim3(NBLOCKS), dim3(NTHREADS), 0, stream,
                     outp, ctx, Wm, bias, dout);
}